// Round 11
// baseline (55.075 us; speedup 1.0000x reference)
//
#include <hip/hip_runtime.h>

// GraphProjection on MI355X (gfx950) — fused, anc-in-registers pass 1.
// x:(8,512,64,64) f32, anchor/sigma:(128,512) f32.
// d_out = nodes (8,512,128) ++ soft_assign (8,128,256).
//
// Round 11: pass 1 restructured. Old pass 1 re-read the 32-KB LDS anc table
// per pixel-thread (64 ds_read_b128/thread/row -> ~6-8K LDS cycles/CU/row,
// the measured bottleneck). New: thread = (4 channels x 4-px quad); rs/ars
// for 4c x 8k live in 64 VGPRs loaded ONCE from global (coalesced float4).
// Cross-lane channel reduction via static-index value-split butterfly
// (63 shfl) + 1-KB red scratch. Pass 2 / staging / finalize unchanged.
// Row loop keeps `#pragma unroll 1` (round-10 spill lesson).

#define NCH 512
#define PARTS 4
#define NROWS 4   // rows per block

typedef __attribute__((address_space(3))) void lds_void_t;
typedef const __attribute__((address_space(1))) void gbl_void_t;

__device__ __forceinline__ void gload_lds16(const float* g, float* l) {
  __builtin_amdgcn_global_load_lds((gbl_void_t*)g, (lds_void_t*)l, 16, 0, 0);
}

struct SharedFused {
  float chunk[NCH * 16];      // 32 KB [c][16px], pixel-quad q stored at q^((c>>2)&3)
  float red[8 * 32];          // 1 KB  [wave][value]  (value = pp*8+k, pq = wave>>1)
  float soft[16 * 8];         // 512 B [px][k] current row
  float soft_all[NROWS * 128];// 2 KB  [row][px][k]
};

__global__ __launch_bounds__(512, 2)
void gp_fused(const float* __restrict__ x,
              const float* __restrict__ anchor,
              const float* __restrict__ sigma,
              float* __restrict__ soft_out,
              float* __restrict__ ws_s1) {
  __shared__ SharedFused sh;
  const int tid = threadIdx.x;
  const int bid = blockIdx.x;       // gx*128 + ((b*4+gy)*4 + part)
  const int gx   = bid >> 7;        // gx-siblings share bid%8 -> same XCD
  const int r    = bid & 127;
  const int part = r & 3;
  const int gy   = (r >> 2) & 3;
  const int b    = r >> 4;
  const int g    = (gy << 2) + gx;
  const int y0   = (gy << 4) + part * NROWS;
  const int x0   = gx << 4;
  const float* xb = x + (size_t)b * (NCH * 4096);

  // pass-1 thread mapping: cs = channel-slice (4 channels), pq = pixel quad
  const int cs   = tid & 127;
  const int pq   = tid >> 7;
  const int c0   = cs << 2;
  const int lane = tid & 63;
  const int wv   = tid >> 6;        // wave = pq*2 + cs-half

  // ---- anchors -> 64 VGPRs (once per kernel; coalesced float4 loads)
  float4 rs4[8], ar4[8];
#pragma unroll
  for (int k = 0; k < 8; ++k) {
    float4 sv = *(const float4*)&sigma [((g << 3) + k) * NCH + c0];
    float4 av = *(const float4*)&anchor[((g << 3) + k) * NCH + c0];
    float4 rv = make_float4(1.0f / sv.x, 1.0f / sv.y, 1.0f / sv.z, 1.0f / sv.w);
    rs4[k] = rv;
    ar4[k] = make_float4(av.x * rv.x, av.y * rv.y, av.z * rv.z, av.w * rv.w);
  }

  auto stage = [&](int row) {           // one 16-px row (32 KB) -> chunk
#pragma unroll
    for (int it = 0; it < 4; ++it) {
      int qf = it * 512 + tid;
      int ci = qf >> 2;
      int qd = qf & 3;
      int qs = qd ^ ((ci >> 2) & 3);
      gload_lds16(xb + (size_t)ci * 4096 + (y0 + row) * 64 + x0 + (qs << 2),
                  &sh.chunk[qf << 2]);
    }
  };

  stage(0);
  asm volatile("s_waitcnt vmcnt(0) lgkmcnt(0)\ns_barrier" ::: "memory");

  float S1[8];
#pragma unroll
  for (int k = 0; k < 8; ++k) S1[k] = 0.0f;

  const int slot = pq ^ (cs & 3);   // LDS quad slot holding logical quad pq
  const int csw2 = (tid >> 2) & 3;  // pass-2 swizzle
  // bit-reversed value id this lane holds after the butterfly
  const int l5   = lane & 31;
  const int vrev = ((l5 & 1) << 4) | ((l5 & 2) << 2) | (l5 & 4) |
                   ((l5 >> 2) & 2) | ((l5 >> 4) & 1);

#pragma unroll 1
  for (int rr = 0; rr < NROWS; ++rr) {
    // ---- pass 1: acc[pp*8+k] over this thread's 4 channels x 4 pixels
    float a[32];
#pragma unroll
    for (int v = 0; v < 32; ++v) a[v] = 0.0f;

#define P1_CH(I, COMP)                                                       \
    {                                                                        \
      float4 xq = *(const float4*)&sh.chunk[((c0 + (I)) << 4) + (slot << 2)];\
      _Pragma("unroll") for (int k = 0; k < 8; ++k) {                        \
        float rk = rs4[k].COMP, ak = ar4[k].COMP;                            \
        float t;                                                             \
        t = fmaf(xq.x, rk, -ak); a[0 * 8 + k] = fmaf(t, t, a[0 * 8 + k]);    \
        t = fmaf(xq.y, rk, -ak); a[1 * 8 + k] = fmaf(t, t, a[1 * 8 + k]);    \
        t = fmaf(xq.z, rk, -ak); a[2 * 8 + k] = fmaf(t, t, a[2 * 8 + k]);    \
        t = fmaf(xq.w, rk, -ak); a[3 * 8 + k] = fmaf(t, t, a[3 * 8 + k]);    \
      }                                                                      \
    }
    P1_CH(0, x) P1_CH(1, y) P1_CH(2, z) P1_CH(3, w)
#undef P1_CH

    // ---- value-split butterfly over the wave's 64 channel-slices
    //      (static indices; double-shfl form avoids runtime-indexed arrays)
#define RLV(MASK, HALF)                                                      \
    { _Pragma("unroll") for (int j = 0; j < (HALF); ++j) {                   \
        float p0 = a[j]          + __shfl_xor(a[j],          MASK, 64);      \
        float p1 = a[j + (HALF)] + __shfl_xor(a[j + (HALF)], MASK, 64);      \
        a[j] = (lane & (MASK)) ? p1 : p0; } }
    RLV(1, 16) RLV(2, 8) RLV(4, 4) RLV(8, 2) RLV(16, 1)
#undef RLV
    a[0] += __shfl_xor(a[0], 32, 64);
    if (lane < 32) sh.red[(wv << 5) + vrev] = a[0];
    asm volatile("s_waitcnt lgkmcnt(0)\ns_barrier" ::: "memory");  // B2

    // ---- softmax over 8 nodes; threads (pq2, v=(pp,k)) = tid<128
    if (tid < 128) {
      const int pq2 = tid >> 5, v = tid & 31;
      float s = sh.red[(pq2 << 6) + v] + sh.red[(pq2 << 6) + 32 + v];
      float l = -0.5f * s;
      float mx = l;
      mx = fmaxf(mx, __shfl_xor(mx, 1, 64));
      mx = fmaxf(mx, __shfl_xor(mx, 2, 64));
      mx = fmaxf(mx, __shfl_xor(mx, 4, 64));
      float e = __expf(l - mx);
      float es = e;
      es += __shfl_xor(es, 1, 64);
      es += __shfl_xor(es, 2, 64);
      es += __shfl_xor(es, 4, 64);
      float sv = e / es;
      const int idx = ((pq2 << 2) + (v >> 3)) * 8 + (v & 7);  // px*8+k
      sh.soft[idx] = sv;
      sh.soft_all[(rr << 7) + idx] = sv;
    }
    asm volatile("s_waitcnt lgkmcnt(0)\ns_barrier" ::: "memory");  // B3

    // ---- pass 2: S1[k] += sum_px chunk[c][px] * soft[px][k]   (c = tid)
    {
      const float* ch = sh.chunk + (tid << 4);
#pragma unroll
      for (int qd = 0; qd < 4; ++qd) {
        float4 xv = *(const float4*)(ch + ((qd ^ csw2) << 2));
#pragma unroll
        for (int j = 0; j < 4; ++j) {
          float xvj = (j == 0) ? xv.x : (j == 1) ? xv.y : (j == 2) ? xv.z : xv.w;
          const float* sp = &sh.soft[((qd << 2) + j) << 3];
          float4 s0 = *(const float4*)sp;
          float4 s1 = *(const float4*)(sp + 4);
          S1[0] = fmaf(xvj, s0.x, S1[0]);
          S1[1] = fmaf(xvj, s0.y, S1[1]);
          S1[2] = fmaf(xvj, s0.z, S1[2]);
          S1[3] = fmaf(xvj, s0.w, S1[3]);
          S1[4] = fmaf(xvj, s1.x, S1[4]);
          S1[5] = fmaf(xvj, s1.y, S1[5]);
          S1[6] = fmaf(xvj, s1.z, S1[6]);
          S1[7] = fmaf(xvj, s1.w, S1[7]);
        }
      }
    }
    asm volatile("s_waitcnt lgkmcnt(0)\ns_barrier" ::: "memory");  // B4

    if (rr + 1 < NROWS) {
      stage(rr + 1);   // other resident block computes while this one stages
      asm volatile("s_waitcnt vmcnt(0)\ns_barrier" ::: "memory");  // chunk ready
    }
  }

  // ---- epilogue: S1 partial (coalesced) + soft_assign from LDS
  const int bg = (b << 4) + g;
  {
    float* wp = ws_s1 + ((size_t)(bg * PARTS + part) << 3) * NCH + tid;
#pragma unroll
    for (int k = 0; k < 8; ++k) wp[k * NCH] = S1[k];
  }
  {
    float* so = soft_out + (size_t)((b << 7) + (g << 3)) * 256 + part * 64;
    int k   = tid >> 6;
    int gpx = tid & 63;
    so[(size_t)k * 256 + gpx] =
        sh.soft_all[((gpx >> 4) << 7) + ((gpx & 15) << 3) + k];
  }
}

// ---------------------------------------------------------------- finalize
__global__ __launch_bounds__(512, 4)
void gp_final(const float* __restrict__ anchor,
              const float* __restrict__ sigma,
              const float* __restrict__ soft_out,
              const float* __restrict__ ws_s1,
              float* __restrict__ nodes_out) {
  const int bg = blockIdx.x;   // b*16+g
  const int b  = bg >> 4, g = bg & 15;
  const int tid = threadIdx.x; // channel c
  __shared__ float sS0[8];
  __shared__ float red[8 * 8];
  __shared__ float invn[8];

  if (tid < 256) {
    int k = tid >> 5, sl = tid & 31;
    const float* sp = soft_out + (size_t)((b << 7) + (g << 3) + k) * 256 + (sl << 3);
    float4 a0 = *(const float4*)sp;
    float4 a1 = *(const float4*)(sp + 4);
    float v = a0.x + a0.y + a0.z + a0.w + a1.x + a1.y + a1.z + a1.w;
    v += __shfl_xor(v, 1, 64);
    v += __shfl_xor(v, 2, 64);
    v += __shfl_xor(v, 4, 64);
    v += __shfl_xor(v, 8, 64);
    v += __shfl_xor(v, 16, 64);
    if (sl == 0) sS0[k] = v;
  }
  __syncthreads();

  float S1[8];
#pragma unroll
  for (int k = 0; k < 8; ++k) S1[k] = 0.0f;
#pragma unroll
  for (int pt = 0; pt < PARTS; ++pt) {
    const float* wp = ws_s1 + ((size_t)(bg * PARTS + pt) << 3) * NCH + tid;
#pragma unroll
    for (int k = 0; k < 8; ++k) S1[k] += wp[k * NCH];
  }

  float v[8];
#pragma unroll
  for (int k = 0; k < 8; ++k) {
    float s  = sigma [((g << 3) + k) * NCH + tid];
    float a  = anchor[((g << 3) + k) * NCH + tid];
    float rs = 1.0f / s;
    float S0 = sS0[k];
    float nd = rs * S1[k] - (a * rs) * S0;
    v[k] = nd / (S0 + 1e-9f);
  }

  const int wv = tid >> 6, lane = tid & 63;
#pragma unroll
  for (int k = 0; k < 8; ++k) {
    float s = v[k] * v[k];
    s += __shfl_xor(s, 1, 64);
    s += __shfl_xor(s, 2, 64);
    s += __shfl_xor(s, 4, 64);
    s += __shfl_xor(s, 8, 64);
    s += __shfl_xor(s, 16, 64);
    s += __shfl_xor(s, 32, 64);
    if (lane == 0) red[(wv << 3) + k] = s;
  }
  __syncthreads();
  if (tid < 8) {
    float t2 = 0.0f;
#pragma unroll
    for (int w = 0; w < 8; ++w) t2 += red[(w << 3) + tid];
    invn[tid] = 1.0f / fmaxf(sqrtf(t2), 1e-12f);
  }
  __syncthreads();

  float4 o0 = make_float4(v[0] * invn[0], v[1] * invn[1], v[2] * invn[2], v[3] * invn[3]);
  float4 o1 = make_float4(v[4] * invn[4], v[5] * invn[5], v[6] * invn[6], v[7] * invn[7]);
  float* dst = nodes_out + ((size_t)(b * NCH) + tid) * 128 + (g << 3);
  *(float4*)(dst)     = o0;
  *(float4*)(dst + 4) = o1;
}

extern "C" void kernel_launch(void* const* d_in, const int* in_sizes, int n_in,
                              void* d_out, int out_size, void* d_ws, size_t ws_size,
                              hipStream_t stream) {
  const float* x      = (const float*)d_in[0];
  const float* anchor = (const float*)d_in[1];
  const float* sigma  = (const float*)d_in[2];
  float* out = (float*)d_out;
  float* wsf = (float*)d_ws;

  const size_t n_nodes = 524288;           // 8*512*128
  float* soft_out = out + n_nodes;
  float* ws_s1  = wsf;                     // 128*4*8*512 floats (8 MB)

  gp_fused<<<512, 512, 0, stream>>>(x, anchor, sigma, soft_out, ws_s1);
  gp_final<<<128, 512, 0, stream>>>(anchor, sigma, soft_out, ws_s1, out);
}